// Round 6
// baseline (165.926 us; speedup 1.0000x reference)
//
#include <hip/hip_runtime.h>
#include <hip/hip_bf16.h>

// x [B=4][C=256][N=4096] fp32 -> attention [B][N][N] fp32 (row softmax of cosine sim)
#define BATCH 4
#define CDIM  256
#define NTOK  4096

#define BM 64      // rows per block
#define BN 128     // tokens per chunk; chunk = 128 tok x K=256 = 64 KB, double-buffered

typedef short bf16x8 __attribute__((ext_vector_type(8)));
typedef float floatx4 __attribute__((ext_vector_type(4)));
typedef unsigned int uintx4 __attribute__((ext_vector_type(4)));
typedef unsigned int u32;

__device__ inline u32 f2bf1(float f) {
    u32 u = __float_as_uint(f);
    u += 0x7fffu + ((u >> 16) & 1u);   // RTNE
    return u >> 16;
}
__device__ inline u32 f2bf2(float lo, float hi) { return f2bf1(lo) | (f2bf1(hi) << 16); }

__device__ inline void gload_lds16(const short* g, short* l) {
    __builtin_amdgcn_global_load_lds(
        (const __attribute__((address_space(1))) u32*)g,
        (__attribute__((address_space(3))) u32*)l, 16, 0, 0);
}

// ---------- prep: x [B][C][N] f32 -> xn [B][N][C] bf16, rows normalized to unit L2 ----------
#define TT 32
__global__ __launch_bounds__(256) void prep_kernel(const float* __restrict__ x,
                                                   short* __restrict__ xn) {
    __shared__ float tile[TT][CDIM + 2];
    __shared__ float part[8][TT];
    __shared__ float rinv_s[TT];
    const int tid = threadIdx.x;
    const int blk = blockIdx.x;            // 0..511
    const int b = blk >> 7;
    const int t0 = (blk & 127) * TT;
    const float* xb = x + (size_t)b * CDIM * NTOK;
    const int ti = tid & 31, cq = tid >> 5;
    float ss = 0.f;
    for (int c = cq; c < CDIM; c += 8) {
        float v = xb[(size_t)c * NTOK + t0 + ti];
        tile[ti][c] = v;
        ss += v * v;
    }
    part[cq][ti] = ss;
    __syncthreads();
    if (tid < TT) {
        float s = 0.f;
#pragma unroll
        for (int q = 0; q < 8; ++q) s += part[q][tid];
        rinv_s[tid] = 1.0f / sqrtf(s);
    }
    __syncthreads();
    const int tok = tid >> 3, seg = tid & 7;
    const float ri = rinv_s[tok];
    size_t obase = ((size_t)(b * NTOK + t0 + tok)) * CDIM + seg * 32;
#pragma unroll
    for (int j = 0; j < 4; ++j) {
        u32 w[4];
#pragma unroll
        for (int u = 0; u < 4; ++u) {
            float f0 = tile[tok][seg * 32 + j * 8 + 2 * u] * ri;
            float f1 = tile[tok][seg * 32 + j * 8 + 2 * u + 1] * ri;
            w[u] = f2bf2(f0, f1);
        }
        *(uintx4*)&xn[obase + j * 8] = (uintx4){w[0], w[1], w[2], w[3]};
    }
}

// ---------- fused two-sweep GEMM + softmax ----------
// Block: 64 rows x 4096 cols, K=256, 1024 threads = 16 waves (2 row x 8 col groups,
// 4 waves/SIMD). A in regs (STATIC indices only). B chunk = 128 tok x 256 k as
// 4 sub-chunks [128][64] (proven 0-conflict swizzle: 16B-pos p of row tr holds
// logical chunk p ^ (tr&7)). Double buffer, stage(ct+1) issued BEFORE compute(ct);
// one __syncthreads per chunk.
__global__ __launch_bounds__(1024, 4) void attn_kernel(const short* __restrict__ xn,
                                                       float* __restrict__ out) {
    __shared__ short Bs[2][4][128][64];      // 2 x 64 KB
    __shared__ float rowsumLds[BM][8];
    const int tid = threadIdx.x;
    const int D = blockIdx.x;                // natural order (proven L2 coherence)
    const int b = D >> 6;
    const int rb = (D & 63) * BM;
    const short* xnb = xn + (size_t)b * NTOK * CDIM;
    float* outb = out + ((size_t)b << 24);
    const int lane = tid & 63, wid = tid >> 6;     // 16 waves: 2 row x 8 col
    const int wr = (wid >> 3) * 32;                // 0 / 32
    const int wcw = (wid & 7) * 16;                // 0,16,...,112
    const int r0 = lane & 15, kq = lane >> 4;

    // staging roles: per quarter, thread -> (row tr = tid>>3 in 0..127, pos tid&7)
    const int str = tid >> 3;                      // 0..127
    const int c8 = (tid & 7) ^ (str & 7);          // inverse-swizzled source 16B-chunk

    // A fragments: rows rb + wr + m*16 + r0, full K=256 in registers (64 VGPR)
    bf16x8 afr[2][8];
#pragma unroll
    for (int m = 0; m < 2; ++m) {
        const short* arow = xnb + (size_t)(rb + wr + m * 16 + r0) * CDIM;
#pragma unroll
        for (int j = 0; j < 8; ++j)
            afr[m][j] = *(const bf16x8*)(arow + j * 32 + kq * 8);
    }

    float psum[2][4] = {{0.f,0.f,0.f,0.f},{0.f,0.f,0.f,0.f}};
    float rinv[2][4];

    // stage chunk ct (128 tok x 256 k) into buffer buf: 4 gloads per thread
    auto stage = [&](int ct, int buf) {
        const short* srcBase = xnb + (size_t)(ct * BN + str) * CDIM + c8 * 8;
#pragma unroll
        for (int kc = 0; kc < 4; ++kc)
            gload_lds16(srcBase + kc * 64, &Bs[buf][kc][(wid << 3) & 127][0]);
    };

    for (int sweep = 0; sweep < 2; ++sweep) {
        stage(0, 0);
        __syncthreads();                      // buffer 0 ready

        for (int ct = 0; ct < 32; ++ct) {
            const int cur = ct & 1;
            if (ct + 1 < 32) stage(ct + 1, cur ^ 1);   // flies during compute

            floatx4 acc[2];
            acc[0] = (floatx4){0.f, 0.f, 0.f, 0.f};
            acc[1] = (floatx4){0.f, 0.f, 0.f, 0.f};

            __builtin_amdgcn_s_setprio(1);
#pragma unroll
            for (int kc = 0; kc < 4; ++kc) {
#pragma unroll
                for (int kk = 0; kk < 2; ++kk) {
                    const int tr = wcw + r0;
                    const int p = ((kk << 2) | kq) ^ (tr & 7);
                    bf16x8 bfr = *(const bf16x8*)&Bs[cur][kc][tr][p * 8];
                    acc[0] = __builtin_amdgcn_mfma_f32_16x16x32_bf16(afr[0][kc*2+kk], bfr, acc[0], 0, 0, 0);
                    acc[1] = __builtin_amdgcn_mfma_f32_16x16x32_bf16(afr[1][kc*2+kk], bfr, acc[1], 0, 0, 0);
                }
            }
            __builtin_amdgcn_s_setprio(0);

            if (sweep == 0) {
#pragma unroll
                for (int m = 0; m < 2; ++m)
#pragma unroll
                    for (int r = 0; r < 4; ++r)
                        psum[m][r] += __expf(acc[m][r] - 1.f);
            } else {
#pragma unroll
                for (int m = 0; m < 2; ++m)
#pragma unroll
                    for (int r = 0; r < 4; ++r) {
                        const int row = rb + wr + m * 16 + kq * 4 + r;
                        float* p = outb + ((size_t)row << 12) + (ct << 7) + wcw + r0;
                        __builtin_nontemporal_store(__expf(acc[m][r] - 1.f) * rinv[m][r], p);
                    }
            }
            __syncthreads();                  // stage(ct+1) drained; buffer swap safe
        } // ct

        if (sweep == 0) {
#pragma unroll
            for (int m = 0; m < 2; ++m)
#pragma unroll
                for (int r = 0; r < 4; ++r) {
                    float v = psum[m][r];
                    v += __shfl_xor(v, 1);
                    v += __shfl_xor(v, 2);
                    v += __shfl_xor(v, 4);
                    v += __shfl_xor(v, 8);
                    if (r0 == 0) rowsumLds[wr + m * 16 + kq * 4 + r][wid & 7] = v;
                }
            __syncthreads();
#pragma unroll
            for (int m = 0; m < 2; ++m)
#pragma unroll
                for (int r = 0; r < 4; ++r) {
                    const int row = wr + m * 16 + kq * 4 + r;
                    float s = 0.f;
#pragma unroll
                    for (int w = 0; w < 8; ++w) s += rowsumLds[row][w];
                    rinv[m][r] = 1.0f / s;
                }
            __syncthreads();
        }
    } // sweep
}

extern "C" void kernel_launch(void* const* d_in, const int* in_sizes, int n_in,
                              void* d_out, int out_size, void* d_ws, size_t ws_size,
                              hipStream_t stream) {
    const float* x = (const float*)d_in[0];
    float* out = (float*)d_out;
    short* xn = (short*)d_ws;    // [B][N][C] bf16 = 8 MB

    prep_kernel<<<BATCH * (NTOK / TT), 256, 0, stream>>>(x, xn);

    attn_kernel<<<NTOK / BM * BATCH, 1024, 0, stream>>>(xn, out);
}

// Round 7
// 160.791 us; speedup vs baseline: 1.0319x; 1.0319x over previous
//
#include <hip/hip_runtime.h>
#include <hip/hip_bf16.h>

// x [B=4][C=256][N=4096] fp32 -> attention [B][N][N] fp32 (row softmax of cosine sim)
#define BATCH 4
#define CDIM  256
#define NTOK  4096

#define BM 64      // rows per block
#define BN 128     // tokens per chunk; chunk = 128 tok x K=256 = 64 KB, double-buffered

typedef short bf16x8 __attribute__((ext_vector_type(8)));
typedef float floatx4 __attribute__((ext_vector_type(4)));
typedef unsigned int uintx4 __attribute__((ext_vector_type(4)));
typedef unsigned int u32;

// Opaque def: prevents LLVM from sinking/rematerializing the fragment load
// into the chunk loop (R2-R6 all had afr demoted to per-chunk VMEM reloads;
// VGPR_Count 60-84 proved it). The asm output cannot be recomputed -> stays in VGPRs.
#define PIN(v) asm volatile("" : "+v"(v))

__device__ inline u32 f2bf1(float f) {
    u32 u = __float_as_uint(f);
    u += 0x7fffu + ((u >> 16) & 1u);   // RTNE
    return u >> 16;
}
__device__ inline u32 f2bf2(float lo, float hi) { return f2bf1(lo) | (f2bf1(hi) << 16); }

__device__ inline void gload_lds16(const short* g, short* l) {
    __builtin_amdgcn_global_load_lds(
        (const __attribute__((address_space(1))) u32*)g,
        (__attribute__((address_space(3))) u32*)l, 16, 0, 0);
}

// ---------- prep: x [B][C][N] f32 -> xn [B][N][C] bf16, rows normalized to unit L2 ----------
#define TT 32
__global__ __launch_bounds__(256) void prep_kernel(const float* __restrict__ x,
                                                   short* __restrict__ xn) {
    __shared__ float tile[TT][CDIM + 2];
    __shared__ float part[8][TT];
    __shared__ float rinv_s[TT];
    const int tid = threadIdx.x;
    const int blk = blockIdx.x;            // 0..511
    const int b = blk >> 7;
    const int t0 = (blk & 127) * TT;
    const float* xb = x + (size_t)b * CDIM * NTOK;
    const int ti = tid & 31, cq = tid >> 5;
    float ss = 0.f;
    for (int c = cq; c < CDIM; c += 8) {
        float v = xb[(size_t)c * NTOK + t0 + ti];
        tile[ti][c] = v;
        ss += v * v;
    }
    part[cq][ti] = ss;
    __syncthreads();
    if (tid < TT) {
        float s = 0.f;
#pragma unroll
        for (int q = 0; q < 8; ++q) s += part[q][tid];
        rinv_s[tid] = 1.0f / sqrtf(s);
    }
    __syncthreads();
    const int tok = tid >> 3, seg = tid & 7;
    const float ri = rinv_s[tok];
    size_t obase = ((size_t)(b * NTOK + t0 + tok)) * CDIM + seg * 32;
#pragma unroll
    for (int j = 0; j < 4; ++j) {
        u32 w[4];
#pragma unroll
        for (int u = 0; u < 4; ++u) {
            float f0 = tile[tok][seg * 32 + j * 8 + 2 * u] * ri;
            float f1 = tile[tok][seg * 32 + j * 8 + 2 * u + 1] * ri;
            w[u] = f2bf2(f0, f1);
        }
        *(uintx4*)&xn[obase + j * 8] = (uintx4){w[0], w[1], w[2], w[3]};
    }
}

// ---------- fused two-sweep GEMM + softmax ----------
// Block: 64 rows x 4096 cols, K=256, 512 threads = 8 waves (2 row x 4 col groups).
// A fragments PINNED in registers (the R2-R6 limiter was their silent reload).
// B chunk = 128 tok x 256 k as 4 sub-chunks [128][64], 0-conflict XOR swizzle
// (16B-pos p of row tr holds logical chunk p ^ (tr&7)). Double buffer,
// stage(ct+1) issued BEFORE compute(ct); one __syncthreads per chunk.
__global__ __launch_bounds__(512, 2) void attn_kernel(const short* __restrict__ xn,
                                                      float* __restrict__ out) {
    __shared__ short Bs[2][4][128][64];      // 2 x 64 KB
    __shared__ float rowsumLds[BM][4];
    const int tid = threadIdx.x;
    const int D = blockIdx.x;                // natural order (proven L2 coherence)
    const int b = D >> 6;
    const int rb = (D & 63) * BM;
    const short* xnb = xn + (size_t)b * NTOK * CDIM;
    float* outb = out + ((size_t)b << 24);
    const int lane = tid & 63, wid = tid >> 6;     // 8 waves: 2 row x 4 col
    const int wr = (wid >> 2) * 32;                // 0 / 32
    const int wc = (wid & 3) * 32;                 // 0 / 32 / 64 / 96
    const int r0 = lane & 15, kq = lane >> 4;

    // staging roles (per wave): rows wid*8 .. wid*8+7 (+64 for h=1)
    const int trl0 = (wid << 3) + (lane >> 3);     // 0..63
    const int c8 = (lane & 7) ^ (lane >> 3);       // inverse-swizzled source 16B-chunk

    // A fragments: rows rb + wr + m*16 + r0, full K=256 in registers, PINNED
    bf16x8 afr[2][8];
#pragma unroll
    for (int m = 0; m < 2; ++m) {
        const short* arow = xnb + (size_t)(rb + wr + m * 16 + r0) * CDIM;
#pragma unroll
        for (int j = 0; j < 8; ++j) {
            afr[m][j] = *(const bf16x8*)(arow + j * 32 + kq * 8);
            PIN(afr[m][j]);
        }
    }

    float psum[2][4] = {{0.f,0.f,0.f,0.f},{0.f,0.f,0.f,0.f}};
    float rinv[2][4];

    // stage chunk ct (128 tok x 256 k) into buffer buf: 8 gloads per lane
    auto stage = [&](int ct, int buf) {
        const short* srcBase = xnb + (size_t)(ct * BN) * CDIM;
#pragma unroll
        for (int kc = 0; kc < 4; ++kc)
#pragma unroll
            for (int h = 0; h < 2; ++h) {
                const short* s = srcBase + (size_t)(h * 64 + trl0) * CDIM + kc * 64 + c8 * 8;
                gload_lds16(s, &Bs[buf][kc][h * 64 + (wid << 3)][0]);
            }
    };

    for (int sweep = 0; sweep < 2; ++sweep) {
        stage(0, 0);
        __syncthreads();                      // buffer 0 ready

        for (int ct = 0; ct < 32; ++ct) {
            const int cur = ct & 1;
            if (ct + 1 < 32) stage(ct + 1, cur ^ 1);   // flies during compute

            floatx4 acc[2][2];
#pragma unroll
            for (int m = 0; m < 2; ++m)
#pragma unroll
                for (int n = 0; n < 2; ++n)
                    acc[m][n] = (floatx4){0.f, 0.f, 0.f, 0.f};

            __builtin_amdgcn_s_setprio(1);
#pragma unroll
            for (int kc = 0; kc < 4; ++kc) {
#pragma unroll
                for (int kk = 0; kk < 2; ++kk) {
                    bf16x8 bfr[2];
#pragma unroll
                    for (int n = 0; n < 2; ++n) {
                        const int tr = wc + n * 16 + r0;
                        const int p = ((kk << 2) | kq) ^ (tr & 7);
                        bfr[n] = *(const bf16x8*)&Bs[cur][kc][tr][p * 8];
                    }
                    acc[0][0] = __builtin_amdgcn_mfma_f32_16x16x32_bf16(afr[0][kc*2+kk], bfr[0], acc[0][0], 0,0,0);
                    acc[1][0] = __builtin_amdgcn_mfma_f32_16x16x32_bf16(afr[1][kc*2+kk], bfr[0], acc[1][0], 0,0,0);
                    acc[0][1] = __builtin_amdgcn_mfma_f32_16x16x32_bf16(afr[0][kc*2+kk], bfr[1], acc[0][1], 0,0,0);
                    acc[1][1] = __builtin_amdgcn_mfma_f32_16x16x32_bf16(afr[1][kc*2+kk], bfr[1], acc[1][1], 0,0,0);
                }
            }
            __builtin_amdgcn_s_setprio(0);

            if (sweep == 0) {
#pragma unroll
                for (int m = 0; m < 2; ++m)
#pragma unroll
                    for (int r = 0; r < 4; ++r)
                        psum[m][r] += __expf(acc[m][0][r] - 1.f) + __expf(acc[m][1][r] - 1.f);
            } else {
#pragma unroll
                for (int m = 0; m < 2; ++m)
#pragma unroll
                    for (int r = 0; r < 4; ++r) {
                        const int row = rb + wr + m * 16 + kq * 4 + r;
                        float* p = outb + ((size_t)row << 12) + (ct << 7) + wc + r0;
                        __builtin_nontemporal_store(__expf(acc[m][0][r] - 1.f) * rinv[m][r], p);
                        __builtin_nontemporal_store(__expf(acc[m][1][r] - 1.f) * rinv[m][r], p + 16);
                    }
            }
            __syncthreads();                  // drains stage(ct+1); buffer swap safe
        } // ct

        if (sweep == 0) {
#pragma unroll
            for (int m = 0; m < 2; ++m)
#pragma unroll
                for (int r = 0; r < 4; ++r) {
                    float v = psum[m][r];
                    v += __shfl_xor(v, 1);
                    v += __shfl_xor(v, 2);
                    v += __shfl_xor(v, 4);
                    v += __shfl_xor(v, 8);
                    if (r0 == 0) rowsumLds[wr + m * 16 + kq * 4 + r][wid & 3] = v;
                }
            __syncthreads();
#pragma unroll
            for (int m = 0; m < 2; ++m)
#pragma unroll
                for (int r = 0; r < 4; ++r) {
                    const int row = wr + m * 16 + kq * 4 + r;
                    rinv[m][r] = 1.0f / (rowsumLds[row][0] + rowsumLds[row][1] +
                                         rowsumLds[row][2] + rowsumLds[row][3]);
                }
            __syncthreads();
        }
    } // sweep
}

extern "C" void kernel_launch(void* const* d_in, const int* in_sizes, int n_in,
                              void* d_out, int out_size, void* d_ws, size_t ws_size,
                              hipStream_t stream) {
    const float* x = (const float*)d_in[0];
    float* out = (float*)d_out;
    short* xn = (short*)d_ws;    // [B][N][C] bf16 = 8 MB

    prep_kernel<<<BATCH * (NTOK / TT), 256, 0, stream>>>(x, xn);

    attn_kernel<<<NTOK / BM * BATCH, 512, 0, stream>>>(xn, out);
}